// Round 13
// baseline (285.696 us; speedup 1.0000x reference)
//
#include <hip/hip_runtime.h>
#include <cstdint>
#include <cstddef>

#define B_ 4
#define S_ 2048
#define D_ 512
#define H_ 8
#define DK_ 64
#define DFF_ 2048

using s16x8  = __attribute__((ext_vector_type(8))) short;
using bf16x8 = __attribute__((ext_vector_type(8))) __bf16;
using f32x4  = __attribute__((ext_vector_type(4))) float;
using f32x16 = __attribute__((ext_vector_type(16))) float;

__device__ __forceinline__ short f2bf(float f) {
  unsigned u = __builtin_bit_cast(unsigned, f);
  u += 0x7FFFu + ((u >> 16) & 1u);
  return (short)(u >> 16);
}
__device__ __forceinline__ float bf2f(short s) {
  unsigned u = ((unsigned)(unsigned short)s) << 16;
  return __builtin_bit_cast(float, u);
}

// v_cvt_pk_bf16_f32: {lo: bf16(a), hi: bf16(b)} in one u32
__device__ __forceinline__ unsigned cvtpk(float a, float b) {
  unsigned r;
  asm("v_cvt_pk_bf16_f32 %0, %1, %2" : "=v"(r) : "v"(a), "v"(b));
  return r;
}
// v_permlane32_swap_b32 a, b: a[32+i] <-> b[i]  (both updated)
__device__ __forceinline__ void pl32swap(unsigned& a, unsigned& b) {
  asm("v_permlane32_swap_b32 %0, %1" : "+v"(a), "+v"(b));
}

// async global->LDS, 16 B per lane. LDS dest = wave-uniform base + lane*16.
__device__ __forceinline__ void gl2lds16(const void* g, void* l) {
  __builtin_amdgcn_global_load_lds(
      (const __attribute__((address_space(1))) void*)g,
      (__attribute__((address_space(3))) void*)l, 16, 0, 0);
}

// ---------------- fused f32 -> bf16 conversion (all tensors, one launch) ----------------
__global__ __launch_bounds__(256)
void cvt_all(const float* __restrict__ x, const float* __restrict__ Wq,
             const float* __restrict__ Wk, const float* __restrict__ Wv,
             const float* __restrict__ Wp, const float* __restrict__ W1,
             const float* __restrict__ W2,
             short* __restrict__ xb, short* __restrict__ wqkv,
             short* __restrict__ wp, short* __restrict__ w1, short* __restrict__ w2) {
  int blk = blockIdx.x;
  const float* src; short* dst; int off;
  if (blk < 4096)      { src = x;  dst = xb;            off = blk; }
  else if (blk < 4352) { src = Wq; dst = wqkv;          off = blk - 4096; }
  else if (blk < 4608) { src = Wk; dst = wqkv + 262144; off = blk - 4352; }
  else if (blk < 4864) { src = Wv; dst = wqkv + 524288; off = blk - 4608; }
  else if (blk < 5120) { src = Wp; dst = wp;            off = blk - 4864; }
  else if (blk < 6144) { src = W1; dst = w1;            off = blk - 5120; }
  else                 { src = W2; dst = w2;            off = blk - 6144; }
  int i = (off * 256 + threadIdx.x) * 4;
  float4 v = *(const float4*)(src + i);
  *(short4*)(dst + i) = make_short4(f2bf(v.x), f2bf(v.y), f2bf(v.z), f2bf(v.w));
}

// ---------------- epilogue helper (gemm256 modes) ----------------
template <int MODE>
__device__ __forceinline__ void gemm_store(int m0, int n, const f32x4& a,
                                           const float* __restrict__ aux1,
                                           void* out0, void* out1, void* out2,
                                           int M, int N) {
  if constexpr (MODE == 0) {
    const int bb = m0 >> 11, ss0 = m0 & 2047;
    if (n < 512) {  // Q^T -> [B,H,64,S], scaled log2e/8 (softmax uses exp2)
      short4 pk = make_short4(f2bf(a[0] * 0.18033688f), f2bf(a[1] * 0.18033688f),
                              f2bf(a[2] * 0.18033688f), f2bf(a[3] * 0.18033688f));
      *(short4*)((short*)out0 +
          ((((size_t)bb * H_ + (n >> 6)) * 64 + (n & 63)) * S_ + ss0)) = pk;
    } else if (n >= 1024) {  // V^T -> [B,H,64,S]
      const int nn = n - 1024;
      short4 pk = make_short4(f2bf(a[0]), f2bf(a[1]), f2bf(a[2]), f2bf(a[3]));
      *(short4*)((short*)out2 +
          ((((size_t)bb * H_ + (nn >> 6)) * 64 + (nn & 63)) * S_ + ss0)) = pk;
    } else {  // K -> [B,H,S,64]
      const int nn = n - 512;
      const size_t rowb = ((size_t)bb * H_ + (nn >> 6)) * S_ + ss0;
#pragma unroll
      for (int rr = 0; rr < 4; ++rr)
        ((short*)out1)[(rowb + rr) * 64 + (nn & 63)] = f2bf(a[rr]);
    }
  } else {  // MODE 2: fast tanh-GELU(acc + bias) -> bf16, native v_exp_f32
#pragma unroll
    for (int rr = 0; rr < 4; ++rr) {
      float t = a[rr] + aux1[n];
      float x2 = t * t;
      float t2 = t * (2.3022082f + 0.1029464f * x2);  // 2*log2e*0.79788*(1+0.044715x^2)
      float e  = __builtin_amdgcn_exp2f(t2);
      float gl = t - t * __builtin_amdgcn_rcpf(1.0f + e);
      ((short*)out0)[(size_t)(m0 + rr) * N + n] = f2bf(gl);
    }
  }
}

// ---------------- v18: 128^2-tile, 512t/8-wave GEMM -> direct bf16 out, no split-K ----------------
__global__ __launch_bounds__(512)
void gemm_out_bf16(const short* __restrict__ A, const short* __restrict__ B,
                   int M, int N, int K, short* __restrict__ out) {
  __shared__ alignas(16) short As[2][128][64];
  __shared__ alignas(16) short Bs[2][128][64];

  const int tid  = threadIdx.x;
  const int lane = tid & 63;
  const int wave = tid >> 6;
  const int quad = lane >> 4;
  const int l16  = lane & 15;
  const int wm   = (wave >> 1) * 32;   // 4 M-groups of 32
  const int wn   = (wave & 1) * 64;    // 2 N-groups of 64
  const int bm   = blockIdx.x * 128;
  const int bn   = blockIdx.y * 128;

  const int srow8 = lane >> 3;
  const int pb    = lane & 7;

  f32x4 acc[2][4] = {};
  const int nt = K >> 6;

#pragma unroll
  for (int i = 0; i < 2; ++i) {
    const int rr = wave * 16 + i * 8 + srow8;
    const int cb = pb ^ (rr & 7);
    gl2lds16(A + (size_t)(bm + rr) * K + cb * 8, &As[0][wave * 16 + i * 8][0]);
    gl2lds16(B + (size_t)(bn + rr) * K + cb * 8, &Bs[0][wave * 16 + i * 8][0]);
  }
  __syncthreads();

  int cur = 0;
  for (int t = 0; t < nt; ++t) {
    if (t + 1 < nt) {
      const int kk = (t + 1) * 64;
#pragma unroll
      for (int i = 0; i < 2; ++i) {
        const int rr = wave * 16 + i * 8 + srow8;
        const int cb = pb ^ (rr & 7);
        gl2lds16(A + (size_t)(bm + rr) * K + kk + cb * 8, &As[cur ^ 1][wave * 16 + i * 8][0]);
        gl2lds16(B + (size_t)(bn + rr) * K + kk + cb * 8, &Bs[cur ^ 1][wave * 16 + i * 8][0]);
      }
    }

#pragma unroll
    for (int c = 0; c < 2; ++c) {
      bf16x8 a[2], b[4];
#pragma unroll
      for (int i = 0; i < 2; ++i) {
        const int row = wm + i * 16 + l16;
        a[i] = __builtin_bit_cast(bf16x8,
            *(const s16x8*)&As[cur][row][(((c * 4 + quad) ^ (row & 7))) * 8]);
      }
#pragma unroll
      for (int j = 0; j < 4; ++j) {
        const int row = wn + j * 16 + l16;
        b[j] = __builtin_bit_cast(bf16x8,
            *(const s16x8*)&Bs[cur][row][(((c * 4 + quad) ^ (row & 7))) * 8]);
      }
#pragma unroll
      for (int i = 0; i < 2; ++i)
#pragma unroll
        for (int j = 0; j < 4; ++j)
          acc[i][j] = __builtin_amdgcn_mfma_f32_16x16x32_bf16(a[i], b[j], acc[i][j], 0, 0, 0);
    }

    __syncthreads();
    cur ^= 1;
  }

#pragma unroll
  for (int i = 0; i < 2; ++i) {
    const int m0 = bm + wm + i * 16 + quad * 4;
#pragma unroll
    for (int j = 0; j < 4; ++j) {
      const int n = bn + wn + j * 16 + l16;
#pragma unroll
      for (int rr = 0; rr < 4; ++rr)
        out[(size_t)(m0 + rr) * N + n] = f2bf(acc[i][j][rr]);
    }
  }
}

// ---------------- v16: 256x256-tile GEMM, 512t, 8 waves (2Mx4N), BK=64, dbuf ----------------
template <int MODE>
__global__ __launch_bounds__(512)
void gemm256(const short* __restrict__ A, const short* __restrict__ B,
             int M, int N, int K,
             const float* __restrict__ aux1,
             void* __restrict__ out0, void* __restrict__ out1, void* __restrict__ out2) {
  __shared__ alignas(16) short As[2][256][64];
  __shared__ alignas(16) short Bs[2][256][64];

  const int tid  = threadIdx.x;
  const int lane = tid & 63;
  const int wave = tid >> 6;
  const int quad = lane >> 4;
  const int l16  = lane & 15;
  const int wm   = (wave >> 2) * 128;
  const int wn   = (wave & 3) * 64;
  const int bm   = blockIdx.x * 256;
  const int bn   = blockIdx.y * 256;

  const int srow8 = lane >> 3;
  const int pb    = lane & 7;

  f32x4 acc[8][4] = {};
  const int nt = K >> 6;

#pragma unroll
  for (int p = 0; p < 4; ++p) {
    const int rr = p * 64 + wave * 8 + srow8;
    const int cb = pb ^ (rr & 7);
    gl2lds16(A + (size_t)(bm + rr) * K + cb * 8, &As[0][p * 64 + wave * 8][0]);
    gl2lds16(B + (size_t)(bn + rr) * K + cb * 8, &Bs[0][p * 64 + wave * 8][0]);
  }
  __syncthreads();

  int cur = 0;
  for (int t = 0; t < nt; ++t) {
    if (t + 1 < nt) {
      const int kk = (t + 1) * 64;
#pragma unroll
      for (int p = 0; p < 4; ++p) {
        const int rr = p * 64 + wave * 8 + srow8;
        const int cb = pb ^ (rr & 7);
        gl2lds16(A + (size_t)(bm + rr) * K + kk + cb * 8, &As[cur ^ 1][p * 64 + wave * 8][0]);
        gl2lds16(B + (size_t)(bn + rr) * K + kk + cb * 8, &Bs[cur ^ 1][p * 64 + wave * 8][0]);
      }
    }

#pragma unroll
    for (int c = 0; c < 2; ++c) {
      bf16x8 a[8], b[4];
#pragma unroll
      for (int i = 0; i < 8; ++i) {
        const int row = wm + i * 16 + l16;
        a[i] = __builtin_bit_cast(bf16x8,
            *(const s16x8*)&As[cur][row][(((c * 4 + quad) ^ (row & 7))) * 8]);
      }
#pragma unroll
      for (int j = 0; j < 4; ++j) {
        const int row = wn + j * 16 + l16;
        b[j] = __builtin_bit_cast(bf16x8,
            *(const s16x8*)&Bs[cur][row][(((c * 4 + quad) ^ (row & 7))) * 8]);
      }
#pragma unroll
      for (int i = 0; i < 8; ++i)
#pragma unroll
        for (int j = 0; j < 4; ++j)
          acc[i][j] = __builtin_amdgcn_mfma_f32_16x16x32_bf16(a[i], b[j], acc[i][j], 0, 0, 0);
    }

    __syncthreads();
    cur ^= 1;
  }

#pragma unroll
  for (int i = 0; i < 8; ++i) {
    const int m0 = bm + wm + i * 16 + quad * 4;
#pragma unroll
    for (int j = 0; j < 4; ++j)
      gemm_store<MODE>(m0, bn + wn + j * 16 + l16, acc[i][j], aux1,
                       out0, out1, out2, M, N);
  }
}

// ---------------- MFMA flash attention v19: 32x32x16 + in-register P (T12) ----------------
// v14 (16x16 + Ps LDS round-trip) plateaued at 56us. v19 per wave-tile
// (32q x 64t): MFMA 32x5cyc -> 16x8cyc; DS ops 29 -> 18 (Ps ELIMINATED);
// LDS 49.6 -> 16.5KB. Layout algebra (verified index-by-index):
//  QK^T = mfma_32x32x16(K, Q): D col=lane&31=q, row t=(reg&3)+8*(reg>>2)+4*hi.
//  PV A-operand needs P[q=l&31][t=s*16+hi*8+j]. Exchange is exactly lane<->
//  lane^32: with w_a = cvtpk(p[8s+2a],p[8s+2a+1]) per lane,
//  permlane32_swap(w0,w2) -> (word0, word2); swap(w1,w3) -> (word1, word3):
//   hi=0: {own w0, own w1, partner w0, partner w1} = t 16s+{0..7}  OK
//   hi=1: {partner w2, partner w3, own w2, own w3} = t 16s+8+{0..7} OK
//  li is lane-local (q=l&31), one shfl_xor(32) at the end.
__global__ __launch_bounds__(512)
void flash_attn_mfma(const short* __restrict__ QTg, const short* __restrict__ Kb,
                     const short* __restrict__ Vtg, const void* __restrict__ mraw,
                     short* __restrict__ ctxb) {
  __shared__ alignas(16) short Ks[64][64];
  __shared__ alignas(16) short Vt[64][64];
  __shared__ alignas(8) unsigned char mbits8[256];
  __shared__ unsigned red[8];

  // XCD chunk swizzle: 256 blocks; 32 consecutive ids = 4 (b,h) K/V panels/XCD.
  int flat = (blockIdx.z * 8 + blockIdx.y) * 8 + blockIdx.x;
  flat = (flat & 7) * 32 + (flat >> 3);
  const int b = flat >> 6, h = (flat >> 3) & 7;
  const int q0 = (flat & 7) * 256;

  const int tid = threadIdx.x;
  const int w = tid >> 6, lane = tid & 63;
  const int l32 = lane & 31, hi = lane >> 5;
  const size_t base  = ((size_t)(b * H_ + h)) * S_ * DK_;  // K   [B,H,S,64]
  const size_t baseT = ((size_t)(b * H_ + h)) * DK_ * S_;  // Q^T/V^T [B,H,64,S]

  // ---- mask: detect dtype, build bitmask row ----
  {
    const unsigned* mw = (const unsigned*)mraw;
    unsigned v = 0;
#pragma unroll
    for (int i = 0; i < 4; ++i) v |= mw[tid + i * 512];
#pragma unroll
    for (int s = 1; s < 64; s <<= 1) v |= __shfl_xor(v, s);
    if (lane == 0) red[w] = v;
    __syncthreads();
    unsigned f = red[0] | red[1] | red[2] | red[3] |
                 red[4] | red[5] | red[6] | red[7];
    if (tid < 256) {
      unsigned byte = 0;
#pragma unroll
      for (int j = 0; j < 8; ++j) {
        int t = tid * 8 + j;
        int gidx = b * S_ + t;
        int val;
        if ((f & ~1u) == 0u)            val = ((const int*)mraw)[gidx];
        else if (f == 0x3F800000u)      val = (((const float*)mraw)[gidx] != 0.0f);
        else                            val = ((const unsigned char*)mraw)[gidx];
        byte |= (val ? 1u : 0u) << j;
      }
      mbits8[tid] = (unsigned char)byte;
    }
  }
  // (first loop barrier fences mbits)

  // Q fragments (B-operand of 32x32x16): lane holds Q[q=l32][k=s4*16+hi*8+j]
  bf16x8 qa[4];
  {
    const int q = q0 + w * 32 + l32;
#pragma unroll
    for (int s4 = 0; s4 < 4; ++s4) {
      s16x8 t;
#pragma unroll
      for (int j = 0; j < 8; ++j)
        t[j] = QTg[baseT + (size_t)(s4 * 16 + hi * 8 + j) * S_ + q];
      qa[s4] = __builtin_bit_cast(bf16x8, t);
    }
  }

  f32x16 Oc[2] = {};
  float li = 0.f;
  const int swzkey = l32 & 7;    // row&7 for all rows this lane reads

  // staging: identical to v14 (row r, chunk cc, XOR key r&7)
  const int r = tid >> 3, cc = tid & 7;
  const short* kp = Kb  + base  + (size_t)r * 64 + cc * 8;
  const short* vp = Vtg + baseT + (size_t)r * S_ + cc * 8;
  const int ch = ((cc ^ (r & 7)) << 3);

  s16x8 kr = *(const s16x8*)(kp);
  s16x8 vr = *(const s16x8*)(vp);

  for (int t0 = 0; t0 < S_; t0 += 64) {
    __syncthreads();
    *(s16x8*)&Ks[r][ch] = kr;
    *(s16x8*)&Vt[r][ch] = vr;
    __syncthreads();

    if (t0 + 64 < S_) {
      kr = *(const s16x8*)(kp + (size_t)(t0 + 64) * 64);
      vr = *(const s16x8*)(vp + (t0 + 64));
    }

    // S^T tiles: sc0 = rows t0+0..31, sc1 = rows t0+32..63 (cols q)
    f32x16 sc0 = {}, sc1 = {};
    __builtin_amdgcn_s_setprio(1);
#pragma unroll
    for (int s4 = 0; s4 < 4; ++s4) {
      const int chn = ((s4 * 2 + hi) ^ swzkey) << 3;
      bf16x8 kb0 = __builtin_bit_cast(bf16x8, *(const s16x8*)&Ks[l32][chn]);
      bf16x8 kb1 = __builtin_bit_cast(bf16x8, *(const s16x8*)&Ks[32 + l32][chn]);
      sc0 = __builtin_amdgcn_mfma_f32_32x32x16_bf16(kb0, qa[s4], sc0, 0, 0, 0);
      sc1 = __builtin_amdgcn_mfma_f32_32x32x16_bf16(kb1, qa[s4], sc1, 0, 0, 0);
    }
    __builtin_amdgcn_s_setprio(0);

    // softmax numerators, masked; lane's t = (reg&3)+8*(reg>>2)+4*hi (+32 for pB)
    const unsigned long long mball =
        *(const unsigned long long*)&mbits8[t0 >> 3];
    float pA[16], pB[16];
#pragma unroll
    for (int rg = 0; rg < 4; ++rg) {
      const unsigned mA = (unsigned)(mball >> (rg * 8 + hi * 4)) & 15u;
      const unsigned mB = (unsigned)(mball >> (32 + rg * 8 + hi * 4)) & 15u;
#pragma unroll
      for (int rr = 0; rr < 4; ++rr) {
        const int reg = rg * 4 + rr;
        float eA = __builtin_amdgcn_exp2f(sc0[reg]);   // Q pre-scaled log2e/8
        float eB = __builtin_amdgcn_exp2f(sc1[reg]);
        pA[reg] = ((mA >> rr) & 1u) ? eA : 0.f;
        pB[reg] = ((mB >> rr) & 1u) ? eB : 0.f;
        li += pA[reg] + pB[reg];
      }
    }

    // PV: per k-slab s4 (t = s4*16 + hi*8 + j): pack P in-register, 2 mfma
    __builtin_amdgcn_s_setprio(1);
#define PVSTEP(S4, PS, BB)                                                    \
    {                                                                         \
      unsigned w0 = cvtpk(PS[BB + 0], PS[BB + 1]);                            \
      unsigned w1 = cvtpk(PS[BB + 2], PS[BB + 3]);                            \
      unsigned w2 = cvtpk(PS[BB + 4], PS[BB + 5]);                            \
      unsigned w3 = cvtpk(PS[BB + 6], PS[BB + 7]);                            \
      pl32swap(w0, w2);                                                       \
      pl32swap(w1, w3);                                                       \
      uint4 pw = make_uint4(w0, w1, w2, w3);                                  \
      bf16x8 pa = __builtin_bit_cast(bf16x8, pw);                             \
      const int chn = (((S4) * 2 + hi) ^ swzkey) << 3;                        \
      bf16x8 vb0 = __builtin_bit_cast(bf16x8, *(const s16x8*)&Vt[l32][chn]);  \
      bf16x8 vb1 = __builtin_bit_cast(bf16x8, *(const s16x8*)&Vt[32 + l32][chn]); \
      Oc[0] = __builtin_amdgcn_mfma_f32_32x32x16_bf16(pa, vb0, Oc[0], 0, 0, 0);   \
      Oc[1] = __builtin_amdgcn_mfma_f32_32x32x16_bf16(pa, vb1, Oc[1], 0, 0, 0);   \
    }
    PVSTEP(0, pA, 0)
    PVSTEP(1, pA, 8)
    PVSTEP(2, pB, 0)
    PVSTEP(3, pB, 8)
#undef PVSTEP
    __builtin_amdgcn_s_setprio(0);
  }

  // normalize + store: lane holds O[q=(reg&3)+8*(reg>>2)+4*hi][d=dt*32+l32]
  li += __shfl_xor(li, 32);          // lane l: total for q = l&31
  float inv[16];
#pragma unroll
  for (int reg = 0; reg < 16; ++reg) {
    const int qq = (reg & 3) + 8 * (reg >> 2) + 4 * hi;
    inv[reg] = 1.f / __shfl(li, qq);
  }
  const size_t rowbase = (size_t)b * S_ + q0 + w * 32;
#pragma unroll
  for (int dt = 0; dt < 2; ++dt)
#pragma unroll
    for (int reg = 0; reg < 16; ++reg) {
      const int qq = (reg & 3) + 8 * (reg >> 2) + 4 * hi;
      ctxb[(rowbase + qq) * (H_ * DK_) + h * 64 + dt * 32 + l32] =
          f2bf(Oc[dt][reg] * inv[reg]);
    }
}

// ---------------- fused residual + LayerNorm (one wave per token) ----------------
__global__ __launch_bounds__(256)
void ln_fused(const float* __restrict__ p0, const float* __restrict__ p1,
              const float* __restrict__ xres, const short* __restrict__ hres,
              const short* __restrict__ hres2,
              const float* __restrict__ bias,
              const float* __restrict__ g, const float* __restrict__ bb,
              float* __restrict__ out32, short* __restrict__ outb) {
  const int wave = threadIdx.x >> 6, lane = threadIdx.x & 63;
  const int token = blockIdx.x * 4 + wave;
  const size_t off = (size_t)token * D_;
  const int c = lane * 8;

  float v[8] = {0.f, 0.f, 0.f, 0.f, 0.f, 0.f, 0.f, 0.f};
  if (p0) {
    float4 a0 = *(const float4*)(p0 + off + c);
    float4 a1 = *(const float4*)(p0 + off + c + 4);
    float4 b0 = *(const float4*)(p1 + off + c);
    float4 b1 = *(const float4*)(p1 + off + c + 4);
    v[0]+=a0.x+b0.x; v[1]+=a0.y+b0.y; v[2]+=a0.z+b0.z; v[3]+=a0.w+b0.w;
    v[4]+=a1.x+b1.x; v[5]+=a1.y+b1.y; v[6]+=a1.z+b1.z; v[7]+=a1.w+b1.w;
  }
  if (xres) {
    float4 x0 = *(const float4*)(xres + off + c);
    float4 x1 = *(const float4*)(xres + off + c + 4);
    v[0]+=x0.x; v[1]+=x0.y; v[2]+=x0.z; v[3]+=x0.w;
    v[4]+=x1.x; v[5]+=x1.y; v[6]+=x1.z; v[7]+=x1.w;
  }
  if (hres) {
    short4 h0 = *(const short4*)(hres + off + c);
    short4 h1 = *(const short4*)(hres + off + c + 4);
    v[0]+=bf2f(h0.x); v[1]+=bf2f(h0.y); v[2]+=bf2f(h0.z); v[3]+=bf2f(h0.w);
    v[4]+=bf2f(h1.x); v[5]+=bf2f(h1.y); v[6]+=bf2f(h1.z); v[7]+=bf2f(h1.w);
  }
  if (hres2) {
    short4 h0 = *(const short4*)(hres2 + off + c);
    short4 h1 = *(const short4*)(hres2 + off + c + 4);
    v[0]+=bf2f(h0.x); v[1]+=bf2f(h0.y); v[2]+=bf2f(h0.z); v[3]+=bf2f(h0.w);
    v[4]+=bf2f(h1.x); v[5]+=bf2f(h1.y); v[6]+=bf2f(h1.z); v[7]+=bf2f(h1.w);
  }
  if (bias) {
    float4 c0 = *(const float4*)(bias + c);
    float4 c1 = *(const float4*)(bias + c + 4);
    v[0]+=c0.x; v[1]+=c0.y; v[2]+=c0.z; v[3]+=c0.w;
    v[4]+=c1.x; v[5]+=c1.y; v[6]+=c1.z; v[7]+=c1.w;
  }

  float sum = 0.f;
#pragma unroll
  for (int i = 0; i < 8; ++i) sum += v[i];
#pragma unroll
  for (int m = 1; m < 64; m <<= 1) sum += __shfl_xor(sum, m);
  float mu = sum * (1.0f / D_);
  float vs = 0.f;
#pragma unroll
  for (int i = 0; i < 8; ++i) { v[i] -= mu; vs += v[i] * v[i]; }
#pragma unroll
  for (int m = 1; m < 64; m <<= 1) vs += __shfl_xor(vs, m);
  float rstd = rsqrtf(vs * (1.0f / D_) + 1e-5f);
#pragma unroll
  for (int i = 0; i < 8; ++i) {
    float val = v[i] * rstd * g[c + i] + bb[c + i];
    if (out32) out32[off + c + i] = val;
    if (outb)  outb[off + c + i] = f2bf(val);
  }
}

// ---------------- workspace layout (bytes) ----------------
constexpr size_t OFF_XB   = 0;                       // [8192,512] bf16
constexpr size_t OFF_WQKV = 8388608;                 // [1536,512] bf16 (Wq|Wk|Wv)
constexpr size_t OFF_WP   = 9961472;                 // [512,512] bf16
constexpr size_t OFF_W1   = 10485760;                // [2048,512] bf16
constexpr size_t OFF_W2   = 12582912;                // [512,2048] bf16
constexpr size_t OFF_QT   = 14680064;                // [B,H,64,S] bf16 (transposed!)
constexpr size_t OFF_K    = 23068672;                // [B,H,S,64] bf16
constexpr size_t OFF_VT   = 31457280;                // [B,H,64,S] bf16 (transposed!)
constexpr size_t OFF_CTX  = 39845888;                // [8192,512] bf16
constexpr size_t OFF_ATT  = 48234496;                // [8192,512] bf16 (Wp out)
constexpr size_t OFF_FF2  = 65011712;                // [8192,512] bf16 (FF2 out)
constexpr size_t OFF_HB   = 81788928;                // [8192,512] bf16 (LN1 out)
constexpr size_t OFF_FF1  = 14680064;                // [8192,2048] bf16 (reuses QT/K/VT/CTX)
constexpr size_t WS_NEED  = 90177536;

extern "C" void kernel_launch(void* const* d_in, const int* in_sizes, int n_in,
                              void* d_out, int out_size, void* d_ws, size_t ws_size,
                              hipStream_t stream) {
  if (ws_size < WS_NEED) return;

  const float* x    = (const float*)d_in[0];
  const void*  msk  = d_in[1];
  const float* Wq   = (const float*)d_in[2];
  const float* Wk   = (const float*)d_in[3];
  const float* Wv   = (const float*)d_in[4];
  const float* Wp   = (const float*)d_in[5];
  const float* W1   = (const float*)d_in[6];
  const float* b1   = (const float*)d_in[7];
  const float* W2   = (const float*)d_in[8];
  const float* b2   = (const float*)d_in[9];
  const float* ln1g = (const float*)d_in[10];
  const float* ln1b = (const float*)d_in[11];
  const float* ln2g = (const float*)d_in[12];
  const float* ln2b = (const float*)d_in[13];

  char* ws = (char*)d_ws;
  short* xb    = (short*)(ws + OFF_XB);
  short* wqkv  = (short*)(ws + OFF_WQKV);
  short* Wpb   = (short*)(ws + OFF_WP);
  short* W1b   = (short*)(ws + OFF_W1);
  short* W2b   = (short*)(ws + OFF_W2);
  short* QTb   = (short*)(ws + OFF_QT);
  short* Kbh   = (short*)(ws + OFF_K);
  short* VTb   = (short*)(ws + OFF_VT);
  short* ctxb  = (short*)(ws + OFF_CTX);
  short* attb  = (short*)(ws + OFF_ATT);
  short* ff2b  = (short*)(ws + OFF_FF2);
  short* hb    = (short*)(ws + OFF_HB);
  short* ff1b  = (short*)(ws + OFF_FF1);

  // all f32->bf16 conversions in one launch
  cvt_all<<<7168, 256, 0, stream>>>(x, Wq, Wk, Wv, Wp, W1, W2,
                                    xb, wqkv, Wpb, W1b, W2b);

  // fused QKV projection: N=1536 (Q^T scaled log2e/8; V^T; K row-major), 256^2 tile
  gemm256<0><<<dim3(32, 6, 1), 512, 0, stream>>>(xb, wqkv, 8192, 1536, 512,
                                                 nullptr, QTb, Kbh, VTb);

  // attention (MFMA flash v19: 32x32x16 + in-register P via cvt_pk/permlane)
  flash_attn_mfma<<<dim3(S_ / 256, H_, B_), 512, 0, stream>>>(QTb, Kbh, VTb, msk, ctxb);

  // output projection -> bf16 att directly (no split-K)
  gemm_out_bf16<<<dim3(64, 4, 1), 512, 0, stream>>>(ctxb, Wpb, 8192, 512, 512, attb);

  // LN1: LN(att + x) -> h (bf16)
  ln_fused<<<2048, 256, 0, stream>>>(nullptr, nullptr, x, attb, nullptr, nullptr,
                                     ln1g, ln1b, nullptr, hb);

  // FF1: fast-gelu(h @ W1^T + b1) -> bf16, 256^2 tile
  gemm256<2><<<dim3(32, 8, 1), 512, 0, stream>>>(hb, W1b, 8192, 2048, 512,
                                                 b1, ff1b, nullptr, nullptr);

  // FF2 -> bf16 directly (no split-K)
  gemm_out_bf16<<<dim3(64, 4, 1), 512, 0, stream>>>(ff1b, W2b, 8192, 512, 2048, ff2b);

  // LN2: LN(ff2 + b2 + h) -> out (f32)
  ln_fused<<<2048, 256, 0, stream>>>(nullptr, nullptr, nullptr, hb, ff2b, b2,
                                     ln2g, ln2b, (float*)d_out, nullptr);
}

// Round 14
// 279.595 us; speedup vs baseline: 1.0218x; 1.0218x over previous
//
#include <hip/hip_runtime.h>
#include <cstdint>
#include <cstddef>

#define B_ 4
#define S_ 2048
#define D_ 512
#define H_ 8
#define DK_ 64
#define DFF_ 2048

using s16x8  = __attribute__((ext_vector_type(8))) short;
using bf16x8 = __attribute__((ext_vector_type(8))) __bf16;
using f32x4  = __attribute__((ext_vector_type(4))) float;

__device__ __forceinline__ short f2bf(float f) {
  unsigned u = __builtin_bit_cast(unsigned, f);
  u += 0x7FFFu + ((u >> 16) & 1u);
  return (short)(u >> 16);
}
__device__ __forceinline__ float bf2f(short s) {
  unsigned u = ((unsigned)(unsigned short)s) << 16;
  return __builtin_bit_cast(float, u);
}

// async global->LDS, 16 B per lane. LDS dest = wave-uniform base + lane*16.
__device__ __forceinline__ void gl2lds16(const void* g, void* l) {
  __builtin_amdgcn_global_load_lds(
      (const __attribute__((address_space(1))) void*)g,
      (__attribute__((address_space(3))) void*)l, 16, 0, 0);
}

// ---------------- fused f32 -> bf16 conversion (all tensors, one launch) ----------------
__global__ __launch_bounds__(256)
void cvt_all(const float* __restrict__ x, const float* __restrict__ Wq,
             const float* __restrict__ Wk, const float* __restrict__ Wv,
             const float* __restrict__ Wp, const float* __restrict__ W1,
             const float* __restrict__ W2,
             short* __restrict__ xb, short* __restrict__ wqkv,
             short* __restrict__ wp, short* __restrict__ w1, short* __restrict__ w2) {
  int blk = blockIdx.x;
  const float* src; short* dst; int off;
  if (blk < 4096)      { src = x;  dst = xb;            off = blk; }
  else if (blk < 4352) { src = Wq; dst = wqkv;          off = blk - 4096; }
  else if (blk < 4608) { src = Wk; dst = wqkv + 262144; off = blk - 4352; }
  else if (blk < 4864) { src = Wv; dst = wqkv + 524288; off = blk - 4608; }
  else if (blk < 5120) { src = Wp; dst = wp;            off = blk - 4864; }
  else if (blk < 6144) { src = W1; dst = w1;            off = blk - 5120; }
  else                 { src = W2; dst = w2;            off = blk - 6144; }
  int i = (off * 256 + threadIdx.x) * 4;
  float4 v = *(const float4*)(src + i);
  *(short4*)(dst + i) = make_short4(f2bf(v.x), f2bf(v.y), f2bf(v.z), f2bf(v.w));
}

// ---------------- epilogue helpers (shared by both GEMM kernels) ----------------
template <int MODE>
__device__ __forceinline__ void gemm_store(int m0, int n, const f32x4& a,
                                           const float* __restrict__ aux1,
                                           void* out0, void* out1, void* out2,
                                           int M, int N, int bz) {
  if constexpr (MODE == 0) {
    const int bb = m0 >> 11, ss0 = m0 & 2047;
    if (n < 512) {  // Q^T -> [B,H,64,S], scaled log2e/8 (softmax uses exp2)
      short4 pk = make_short4(f2bf(a[0] * 0.18033688f), f2bf(a[1] * 0.18033688f),
                              f2bf(a[2] * 0.18033688f), f2bf(a[3] * 0.18033688f));
      *(short4*)((short*)out0 +
          ((((size_t)bb * H_ + (n >> 6)) * 64 + (n & 63)) * S_ + ss0)) = pk;
    } else if (n >= 1024) {  // V^T -> [B,H,64,S]
      const int nn = n - 1024;
      short4 pk = make_short4(f2bf(a[0]), f2bf(a[1]), f2bf(a[2]), f2bf(a[3]));
      *(short4*)((short*)out2 +
          ((((size_t)bb * H_ + (nn >> 6)) * 64 + (nn & 63)) * S_ + ss0)) = pk;
    } else {  // K -> [B,H,S,64]
      const int nn = n - 512;
      const size_t rowb = ((size_t)bb * H_ + (nn >> 6)) * S_ + ss0;
#pragma unroll
      for (int rr = 0; rr < 4; ++rr)
        ((short*)out1)[(rowb + rr) * 64 + (nn & 63)] = f2bf(a[rr]);
    }
  } else if constexpr (MODE == 1) {  // f32 split-K partial
    float* dst = (float*)out0 + (size_t)bz * M * N;
#pragma unroll
    for (int rr = 0; rr < 4; ++rr)
      dst[(size_t)(m0 + rr) * N + n] = a[rr];
  } else {  // MODE 2: fast tanh-GELU(acc + bias) -> bf16, native v_exp_f32
#pragma unroll
    for (int rr = 0; rr < 4; ++rr) {
      float t = a[rr] + aux1[n];
      float x2 = t * t;
      float t2 = t * (2.3022082f + 0.1029464f * x2);  // 2*log2e*0.79788*(1+0.044715x^2)
      float e  = __builtin_amdgcn_exp2f(t2);
      float gl = t - t * __builtin_amdgcn_rcpf(1.0f + e);
      ((short*)out0)[(size_t)(m0 + rr) * N + n] = f2bf(gl);
    }
  }
}

// ---------------- bf16 MFMA GEMM: 256t, 128x128 tile, BK=64, dbuf (v15) ----------------
// Kept for the N=512 GEMMs (Wp, FF2) where a 256^2 grid would cover 25% of CUs.
template <int MODE>
__global__ __launch_bounds__(256)
void gemm_bt(const short* __restrict__ A, const short* __restrict__ B,
             int M, int N, int K,
             const float* __restrict__ aux1,
             void* __restrict__ out0, void* __restrict__ out1, void* __restrict__ out2) {
  __shared__ alignas(16) short As[2][128][64];
  __shared__ alignas(16) short Bs[2][128][64];

  const int tid  = threadIdx.x;
  const int lane = tid & 63;
  const int wave = tid >> 6;
  const int quad = lane >> 4;
  const int l16  = lane & 15;
  const int wm   = (wave >> 1) * 64;
  const int wn   = (wave & 1) * 64;
  const int bm   = blockIdx.x * 128;
  const int bn   = blockIdx.y * 128;
  const int Kh   = K / gridDim.z;
  const int koff = blockIdx.z * Kh;

  const int srow8 = lane >> 3;   // row within an 8-row staging chunk
  const int pb    = lane & 7;    // physical 16B block within 128B row

  f32x4 acc[4][4] = {};
  const int nt = Kh >> 6;

  // prologue: stage tile 0 into buf 0
#pragma unroll
  for (int i = 0; i < 4; ++i) {
    const int rr = wave * 32 + i * 8 + srow8;
    const int cb = pb ^ (rr & 7);
    gl2lds16(A + (size_t)(bm + rr) * K + koff + cb * 8, &As[0][wave * 32 + i * 8][0]);
    gl2lds16(B + (size_t)(bn + rr) * K + koff + cb * 8, &Bs[0][wave * 32 + i * 8][0]);
  }
  __syncthreads();

  int cur = 0;
  for (int t = 0; t < nt; ++t) {
    if (t + 1 < nt) {
      const int kk = koff + (t + 1) * 64;
#pragma unroll
      for (int i = 0; i < 4; ++i) {
        const int rr = wave * 32 + i * 8 + srow8;
        const int cb = pb ^ (rr & 7);
        gl2lds16(A + (size_t)(bm + rr) * K + kk + cb * 8, &As[cur ^ 1][wave * 32 + i * 8][0]);
        gl2lds16(B + (size_t)(bn + rr) * K + kk + cb * 8, &Bs[cur ^ 1][wave * 32 + i * 8][0]);
      }
    }

#pragma unroll
    for (int c = 0; c < 2; ++c) {
      bf16x8 a[4], b[4];
#pragma unroll
      for (int i = 0; i < 4; ++i) {
        const int row = wm + i * 16 + l16;
        a[i] = __builtin_bit_cast(bf16x8,
            *(const s16x8*)&As[cur][row][(((c * 4 + quad) ^ (row & 7))) * 8]);
      }
#pragma unroll
      for (int j = 0; j < 4; ++j) {
        const int row = wn + j * 16 + l16;
        b[j] = __builtin_bit_cast(bf16x8,
            *(const s16x8*)&Bs[cur][row][(((c * 4 + quad) ^ (row & 7))) * 8]);
      }
#pragma unroll
      for (int i = 0; i < 4; ++i)
#pragma unroll
        for (int j = 0; j < 4; ++j)
          acc[i][j] = __builtin_amdgcn_mfma_f32_16x16x32_bf16(a[i], b[j], acc[i][j], 0, 0, 0);
    }

    __syncthreads();
    cur ^= 1;
  }

#pragma unroll
  for (int i = 0; i < 4; ++i) {
    const int m0 = bm + wm + i * 16 + quad * 4;
#pragma unroll
    for (int j = 0; j < 4; ++j)
      gemm_store<MODE>(m0, bn + wn + j * 16 + l16, acc[i][j], aux1,
                       out0, out1, out2, M, N, blockIdx.z);
  }
}

// ---------------- v16: 256x256-tile GEMM, 512t, 8 waves (2Mx4N), BK=64, dbuf ----------------
// Best-measured for the large GEMMs (QKV N=1536, FF1 N=2048).
template <int MODE>
__global__ __launch_bounds__(512)
void gemm256(const short* __restrict__ A, const short* __restrict__ B,
             int M, int N, int K,
             const float* __restrict__ aux1,
             void* __restrict__ out0, void* __restrict__ out1, void* __restrict__ out2) {
  __shared__ alignas(16) short As[2][256][64];
  __shared__ alignas(16) short Bs[2][256][64];

  const int tid  = threadIdx.x;
  const int lane = tid & 63;
  const int wave = tid >> 6;
  const int quad = lane >> 4;
  const int l16  = lane & 15;
  const int wm   = (wave >> 2) * 128;   // 2 M-groups of 128
  const int wn   = (wave & 3) * 64;     // 4 N-groups of 64
  const int bm   = blockIdx.x * 256;
  const int bn   = blockIdx.y * 256;

  const int srow8 = lane >> 3;   // row within an 8-row staging chunk
  const int pb    = lane & 7;    // physical 16B block within 128B row

  f32x4 acc[8][4] = {};
  const int nt = K >> 6;

  // prologue: stage tile 0 (4 passes of 64 rows each for A and B)
#pragma unroll
  for (int p = 0; p < 4; ++p) {
    const int rr = p * 64 + wave * 8 + srow8;
    const int cb = pb ^ (rr & 7);
    gl2lds16(A + (size_t)(bm + rr) * K + cb * 8, &As[0][p * 64 + wave * 8][0]);
    gl2lds16(B + (size_t)(bn + rr) * K + cb * 8, &Bs[0][p * 64 + wave * 8][0]);
  }
  __syncthreads();

  int cur = 0;
  for (int t = 0; t < nt; ++t) {
    if (t + 1 < nt) {
      const int kk = (t + 1) * 64;
#pragma unroll
      for (int p = 0; p < 4; ++p) {
        const int rr = p * 64 + wave * 8 + srow8;
        const int cb = pb ^ (rr & 7);
        gl2lds16(A + (size_t)(bm + rr) * K + kk + cb * 8, &As[cur ^ 1][p * 64 + wave * 8][0]);
        gl2lds16(B + (size_t)(bn + rr) * K + kk + cb * 8, &Bs[cur ^ 1][p * 64 + wave * 8][0]);
      }
    }

#pragma unroll
    for (int c = 0; c < 2; ++c) {
      bf16x8 a[8], b[4];
#pragma unroll
      for (int i = 0; i < 8; ++i) {
        const int row = wm + i * 16 + l16;
        a[i] = __builtin_bit_cast(bf16x8,
            *(const s16x8*)&As[cur][row][(((c * 4 + quad) ^ (row & 7))) * 8]);
      }
#pragma unroll
      for (int j = 0; j < 4; ++j) {
        const int row = wn + j * 16 + l16;
        b[j] = __builtin_bit_cast(bf16x8,
            *(const s16x8*)&Bs[cur][row][(((c * 4 + quad) ^ (row & 7))) * 8]);
      }
#pragma unroll
      for (int i = 0; i < 8; ++i)
#pragma unroll
        for (int j = 0; j < 4; ++j)
          acc[i][j] = __builtin_amdgcn_mfma_f32_16x16x32_bf16(a[i], b[j], acc[i][j], 0, 0, 0);
    }

    __syncthreads();
    cur ^= 1;
  }

#pragma unroll
  for (int i = 0; i < 8; ++i) {
    const int m0 = bm + wm + i * 16 + quad * 4;
#pragma unroll
    for (int j = 0; j < 4; ++j)
      gemm_store<MODE>(m0, bn + wn + j * 16 + l16, acc[i][j], aux1,
                       out0, out1, out2, M, N, 0);
  }
}

// ---------------- MFMA flash attention v14: 8 waves x 2 q-strips (256 q/block) ----------------
// Best-measured flash (56.1us). v19's 32x32+in-register-P variant was
// functionally correct but SLOWER (59.8us, conflicts 2.1M->4.2M: both lane
// halves read the same 32 rows per fragment read). Reverted.
__global__ __launch_bounds__(512)
void flash_attn_mfma(const short* __restrict__ QTg, const short* __restrict__ Kb,
                     const short* __restrict__ Vtg, const void* __restrict__ mraw,
                     short* __restrict__ ctxb) {
  __shared__ alignas(16) short Ks[64][64];
  __shared__ alignas(16) short Vt[64][64];
  __shared__ alignas(16) short Ps[8][32][64];
  __shared__ alignas(8) unsigned char mbits8[256];
  __shared__ unsigned red[8];

  // XCD chunk swizzle: 256 blocks; 32 consecutive ids = 4 full (b,h) K/V
  // panels (2MB < 4MB L2) per XCD.
  int flat = (blockIdx.z * 8 + blockIdx.y) * 8 + blockIdx.x;
  flat = (flat & 7) * 32 + (flat >> 3);
  const int b = flat >> 6, h = (flat >> 3) & 7;
  const int q0 = (flat & 7) * 256;

  const int tid = threadIdx.x;
  const int w = tid >> 6, lane = tid & 63;
  const int quad = lane >> 4, l16 = lane & 15;
  const size_t base  = ((size_t)(b * H_ + h)) * S_ * DK_;  // K   [B,H,S,64]
  const size_t baseT = ((size_t)(b * H_ + h)) * DK_ * S_;  // Q^T/V^T [B,H,64,S]

  // ---- mask: detect dtype (OR of first 2048 words), build bitmask row ----
  {
    const unsigned* mw = (const unsigned*)mraw;
    unsigned v = 0;
#pragma unroll
    for (int i = 0; i < 4; ++i) v |= mw[tid + i * 512];
#pragma unroll
    for (int s = 1; s < 64; s <<= 1) v |= __shfl_xor(v, s);
    if (lane == 0) red[w] = v;
    __syncthreads();
    unsigned f = red[0] | red[1] | red[2] | red[3] |
                 red[4] | red[5] | red[6] | red[7];
    if (tid < 256) {               // no barrier inside: safe divergence
      unsigned byte = 0;
#pragma unroll
      for (int j = 0; j < 8; ++j) {
        int t = tid * 8 + j;              // 0..2047
        int gidx = b * S_ + t;
        int val;
        if ((f & ~1u) == 0u)            val = ((const int*)mraw)[gidx];
        else if (f == 0x3F800000u)      val = (((const float*)mraw)[gidx] != 0.0f);
        else                            val = ((const unsigned char*)mraw)[gidx];
        byte |= (val ? 1u : 0u) << j;
      }
      mbits8[tid] = (unsigned char)byte;
    }
  }
  // (first loop barrier fences mbits)

  // Q fragments (B-operand): strip st: col q = q0 + w*32 + st*16 + l16
  bf16x8 qa[2][2];
#pragma unroll
  for (int st = 0; st < 2; ++st) {
    const int q = q0 + w * 32 + st * 16 + l16;
#pragma unroll
    for (int c = 0; c < 2; ++c) {
      s16x8 t;
#pragma unroll
      for (int j = 0; j < 8; ++j)
        t[j] = QTg[baseT + (size_t)(c * 32 + quad * 8 + j) * S_ + q];
      qa[st][c] = __builtin_bit_cast(bf16x8, t);
    }
  }

  f32x4 Oc[2][4] = {};
  float li[2] = {};               // per-lane partial: q = l16 (per strip)
  const int swz = l16 & 7;

  // staging: row r (t for K, d for V), one 16B chunk cc per thread, XOR key r&7
  const int r = tid >> 3, cc = tid & 7;
  const short* kp = Kb  + base  + (size_t)r * 64 + cc * 8;
  const short* vp = Vtg + baseT + (size_t)r * S_ + cc * 8;
  const int ch = ((cc ^ (r & 7)) << 3);

  // preload tile 0
  s16x8 kr = *(const s16x8*)(kp);
  s16x8 vr = *(const s16x8*)(vp);

  for (int t0 = 0; t0 < S_; t0 += 64) {
    __syncthreads();  // prev tile consumers done (also fences mbits on iter 0)
    *(s16x8*)&Ks[r][ch] = kr;
    *(s16x8*)&Vt[r][ch] = vr;
    __syncthreads();

    if (t0 + 64 < S_) {  // prefetch next tile during compute
      kr = *(const s16x8*)(kp + (size_t)(t0 + 64) * 64);
      vr = *(const s16x8*)(vp + (t0 + 64));
    }

    // S^T = K Q : sc[st][jt][rr] = S[t=jt*16+quad*4+rr][q=l16 of strip st]
    f32x4 sc[2][4] = {};
    __builtin_amdgcn_s_setprio(1);
#pragma unroll
    for (int c = 0; c < 2; ++c) {
#pragma unroll
      for (int jt = 0; jt < 4; ++jt) {
        bf16x8 kb = __builtin_bit_cast(bf16x8,
            *(const s16x8*)&Ks[jt * 16 + l16][((c * 4 + quad) ^ swz) << 3]);
        sc[0][jt] = __builtin_amdgcn_mfma_f32_16x16x32_bf16(kb, qa[0][c], sc[0][jt], 0, 0, 0);
        sc[1][jt] = __builtin_amdgcn_mfma_f32_16x16x32_bf16(kb, qa[1][c], sc[1][jt], 0, 0, 0);
      }
    }
    __builtin_amdgcn_s_setprio(0);

    // softmax numerators + packed Ps writes (k = jt*16+quad*4+rr, q = l16)
    const unsigned long long mball =
        *(const unsigned long long*)&mbits8[t0 >> 3];
#pragma unroll
    for (int jt = 0; jt < 4; ++jt) {
      const unsigned m16 = ((unsigned)(mball >> (jt * 16))) >> (quad * 4);
      const int pch = (((jt * 2 + (quad >> 1)) ^ swz) << 3) + (quad & 1) * 4;
#pragma unroll
      for (int st = 0; st < 2; ++st) {
        unsigned uu[4];
#pragma unroll
        for (int rr = 0; rr < 4; ++rr) {
          float pe = __builtin_amdgcn_exp2f(sc[st][jt][rr]);  // Q pre-scaled log2e/8
          unsigned u = __builtin_bit_cast(unsigned, pe) & 0xFFFF0000u;
          u = ((m16 >> rr) & 1u) ? u : 0u;
          li[st] += __builtin_bit_cast(float, u);
          uu[rr] = u;
        }
        *(uint2*)&Ps[w][st * 16 + l16][pch] =
            make_uint2(__builtin_amdgcn_perm(uu[1], uu[0], 0x07060302u),
                       __builtin_amdgcn_perm(uu[3], uu[2], 0x07060302u));
      }
    }

    // O += P V (Ps rows = q; read with same XOR key l16&7)
    __builtin_amdgcn_s_setprio(1);
#pragma unroll
    for (int c = 0; c < 2; ++c) {
      bf16x8 pa0 = __builtin_bit_cast(bf16x8,
          *(const s16x8*)&Ps[w][l16][((c * 4 + quad) ^ swz) << 3]);
      bf16x8 pa1 = __builtin_bit_cast(bf16x8,
          *(const s16x8*)&Ps[w][16 + l16][((c * 4 + quad) ^ swz) << 3]);
#pragma unroll
      for (int dt = 0; dt < 4; ++dt) {
        bf16x8 vb = __builtin_bit_cast(bf16x8,
            *(const s16x8*)&Vt[dt * 16 + l16][((c * 4 + quad) ^ swz) << 3]);
        Oc[0][dt] = __builtin_amdgcn_mfma_f32_16x16x32_bf16(pa0, vb, Oc[0][dt], 0, 0, 0);
        Oc[1][dt] = __builtin_amdgcn_mfma_f32_16x16x32_bf16(pa1, vb, Oc[1][dt], 0, 0, 0);
      }
    }
    __builtin_amdgcn_s_setprio(0);
  }

#pragma unroll
  for (int st = 0; st < 2; ++st) {
    float l = li[st];
    l += __shfl_xor(l, 16);    // reduce partial sums across the 4 quads
    l += __shfl_xor(l, 32);    // -> every lane: total for q = l16
#pragma unroll
    for (int rr = 0; rr < 4; ++rr) {
      float lr = __shfl(l, quad * 4 + rr);   // total for q-row quad*4+rr
      float inv = 1.f / lr;
      const size_t row = (size_t)b * S_ + q0 + w * 32 + st * 16 + quad * 4 + rr;
#pragma unroll
      for (int dt = 0; dt < 4; ++dt)
        ctxb[row * (H_ * DK_) + h * 64 + dt * 16 + l16] = f2bf(Oc[st][dt][rr] * inv);
    }
  }
}

// ---------------- fused split-K reduce + LayerNorm (one wave per token) ----------------
__global__ __launch_bounds__(256)
void ln_fused(const float* __restrict__ p0, const float* __restrict__ p1,
              const float* __restrict__ xres, const short* __restrict__ hres,
              const float* __restrict__ bias,
              const float* __restrict__ g, const float* __restrict__ bb,
              float* __restrict__ out32, short* __restrict__ outb) {
  const int wave = threadIdx.x >> 6, lane = threadIdx.x & 63;
  const int token = blockIdx.x * 4 + wave;
  const size_t off = (size_t)token * D_;
  const int c = lane * 8;

  float v[8];
  {
    float4 a0 = *(const float4*)(p0 + off + c);
    float4 a1 = *(const float4*)(p0 + off + c + 4);
    float4 b0 = *(const float4*)(p1 + off + c);
    float4 b1 = *(const float4*)(p1 + off + c + 4);
    v[0]=a0.x+b0.x; v[1]=a0.y+b0.y; v[2]=a0.z+b0.z; v[3]=a0.w+b0.w;
    v[4]=a1.x+b1.x; v[5]=a1.y+b1.y; v[6]=a1.z+b1.z; v[7]=a1.w+b1.w;
  }
  if (xres) {
    float4 x0 = *(const float4*)(xres + off + c);
    float4 x1 = *(const float4*)(xres + off + c + 4);
    v[0]+=x0.x; v[1]+=x0.y; v[2]+=x0.z; v[3]+=x0.w;
    v[4]+=x1.x; v[5]+=x1.y; v[6]+=x1.z; v[7]+=x1.w;
  }
  if (hres) {
    short4 h0 = *(const short4*)(hres + off + c);
    short4 h1 = *(const short4*)(hres + off + c + 4);
    v[0]+=bf2f(h0.x); v[1]+=bf2f(h0.y); v[2]+=bf2f(h0.z); v[3]+=bf2f(h0.w);
    v[4]+=bf2f(h1.x); v[5]+=bf2f(h1.y); v[6]+=bf2f(h1.z); v[7]+=bf2f(h1.w);
  }
  if (bias) {
    float4 c0 = *(const float4*)(bias + c);
    float4 c1 = *(const float4*)(bias + c + 4);
    v[0]+=c0.x; v[1]+=c0.y; v[2]+=c0.z; v[3]+=c0.w;
    v[4]+=c1.x; v[5]+=c1.y; v[6]+=c1.z; v[7]+=c1.w;
  }

  float sum = 0.f;
#pragma unroll
  for (int i = 0; i < 8; ++i) sum += v[i];
#pragma unroll
  for (int m = 1; m < 64; m <<= 1) sum += __shfl_xor(sum, m);
  float mu = sum * (1.0f / D_);
  float vs = 0.f;
#pragma unroll
  for (int i = 0; i < 8; ++i) { v[i] -= mu; vs += v[i] * v[i]; }
#pragma unroll
  for (int m = 1; m < 64; m <<= 1) vs += __shfl_xor(vs, m);
  float rstd = rsqrtf(vs * (1.0f / D_) + 1e-5f);
#pragma unroll
  for (int i = 0; i < 8; ++i) {
    float val = v[i] * rstd * g[c + i] + bb[c + i];
    if (out32) out32[off + c + i] = val;
    if (outb)  outb[off + c + i] = f2bf(val);
  }
}

// ---------------- workspace layout (bytes) ----------------
constexpr size_t OFF_XB   = 0;                       // [8192,512] bf16
constexpr size_t OFF_WQKV = 8388608;                 // [1536,512] bf16 (Wq|Wk|Wv)
constexpr size_t OFF_WP   = 9961472;                 // [512,512] bf16
constexpr size_t OFF_W1   = 10485760;                // [2048,512] bf16
constexpr size_t OFF_W2   = 12582912;                // [512,2048] bf16
constexpr size_t OFF_QT   = 14680064;                // [B,H,64,S] bf16 (transposed!)
constexpr size_t OFF_K    = 23068672;                // [B,H,S,64] bf16
constexpr size_t OFF_VT   = 31457280;                // [B,H,64,S] bf16 (transposed!)
constexpr size_t OFF_CTX  = 39845888;                // [8192,512] bf16
constexpr size_t OFF_P0   = 48234496;                // [8192,512] f32 split-K partial 0
constexpr size_t OFF_P1   = 65011712;                // [8192,512] f32 split-K partial 1
constexpr size_t OFF_HB   = 81788928;                // [8192,512] bf16 (LN1 out)
constexpr size_t OFF_FF1  = 14680064;                // [8192,2048] bf16 (reuses QT/K/VT/CTX)
constexpr size_t WS_NEED  = 90177536;

extern "C" void kernel_launch(void* const* d_in, const int* in_sizes, int n_in,
                              void* d_out, int out_size, void* d_ws, size_t ws_size,
                              hipStream_t stream) {
  if (ws_size < WS_NEED) return;

  const float* x    = (const float*)d_in[0];
  const void*  msk  = d_in[1];
  const float* Wq   = (const float*)d_in[2];
  const float* Wk   = (const float*)d_in[3];
  const float* Wv   = (const float*)d_in[4];
  const float* Wp   = (const float*)d_in[5];
  const float* W1   = (const float*)d_in[6];
  const float* b1   = (const float*)d_in[7];
  const float* W2   = (const float*)d_in[8];
  const float* b2   = (const float*)d_in[9];
  const float* ln1g = (const float*)d_in[10];
  const float* ln1b = (const float*)d_in[11];
  const float* ln2g = (const float*)d_in[12];
  const float* ln2b = (const float*)d_in[13];

  char* ws = (char*)d_ws;
  short* xb    = (short*)(ws + OFF_XB);
  short* wqkv  = (short*)(ws + OFF_WQKV);
  short* Wpb   = (short*)(ws + OFF_WP);
  short* W1b   = (short*)(ws + OFF_W1);
  short* W2b   = (short*)(ws + OFF_W2);
  short* QTb   = (short*)(ws + OFF_QT);
  short* Kbh   = (short*)(ws + OFF_K);
  short* VTb   = (short*)(ws + OFF_VT);
  short* ctxb  = (short*)(ws + OFF_CTX);
  float* p0    = (float*)(ws + OFF_P0);   // split-K partials (P0|P1 contiguous)
  short* hb    = (short*)(ws + OFF_HB);
  short* ff1b  = (short*)(ws + OFF_FF1);

  // all f32->bf16 conversions in one launch
  cvt_all<<<7168, 256, 0, stream>>>(x, Wq, Wk, Wv, Wp, W1, W2,
                                    xb, wqkv, Wpb, W1b, W2b);

  // fused QKV projection: N=1536 (Q^T scaled log2e/8; V^T; K row-major), 256^2 tile
  gemm256<0><<<dim3(32, 6, 1), 512, 0, stream>>>(xb, wqkv, 8192, 1536, 512,
                                                 nullptr, QTb, Kbh, VTb);

  // attention (MFMA flash v14: 8 waves x 2 q-strips, 256 q/block)
  flash_attn_mfma<<<dim3(S_ / 256, H_, B_), 512, 0, stream>>>(QTb, Kbh, VTb, msk, ctxb);

  // output projection, split-K=2 -> f32 partials (reduce+residual in LN1)
  gemm_bt<1><<<dim3(64, 4, 2), 256, 0, stream>>>(ctxb, Wpb, 8192, 512, 512,
                                                 nullptr, p0, nullptr, nullptr);

  // LN1: LN(p0 + p1 + x) -> h (bf16)
  ln_fused<<<2048, 256, 0, stream>>>(p0, p0 + (size_t)8192 * 512, x, nullptr, nullptr,
                                     ln1g, ln1b, nullptr, hb);

  // FF1: fast-gelu(h @ W1^T + b1) -> bf16, 256^2 tile
  gemm256<2><<<dim3(32, 8, 1), 512, 0, stream>>>(hb, W1b, 8192, 2048, 512,
                                                 b1, ff1b, nullptr, nullptr);

  // FF2: split-K=2 -> f32 partials (reduce+bias+residual in LN2)
  gemm_bt<1><<<dim3(64, 4, 2), 256, 0, stream>>>(ff1b, W2b, 8192, 512, 2048,
                                                 nullptr, p0, nullptr, nullptr);

  // LN2: LN(p0 + p1 + b2 + h) -> out (f32)
  ln_fused<<<2048, 256, 0, stream>>>(p0, p0 + (size_t)8192 * 512, nullptr, hb, b2,
                                     ln2g, ln2b, (float*)d_out, nullptr);
}